// Round 2
// baseline (104.827 us; speedup 1.0000x reference)
//
#include <hip/hip_runtime.h>
#include <hip/hip_bf16.h>
#include <math.h>

#define N 8192
#define D 128
#define MARGIN 0.3f

#define NSTRIP 64            // 128-row strips
#define CPS 12               // j-chunk blocks per strip (8x11 + 4x10 = 128 j-tiles)
#define GRID_MAIN (NSTRIP * CPS)   // 768 = 3 blocks/CU exactly

typedef float f32x4 __attribute__((ext_vector_type(4)));
typedef short bf16x8 __attribute__((ext_vector_type(8)));
typedef unsigned short u16x8 __attribute__((ext_vector_type(8)));

#define AS1 __attribute__((address_space(1)))
#define AS3 __attribute__((address_space(3)))

__device__ inline void gload_lds16(const void* g, void* l) {
    __builtin_amdgcn_global_load_lds((AS1 void*)(void*)(g), (AS3 void*)(l), 16, 0, 0);
}

__device__ inline unsigned short f2bf(float f) {
    unsigned u = __float_as_uint(f);
    unsigned r = (u + 0x7FFFu + ((u >> 16) & 1u)) >> 16;
    return (unsigned short)r;
}

// ---------- convert fp32 -> bf16 + row norms + init mining arrays ----------
__global__ __launch_bounds__(256) void convert_kernel(const float* __restrict__ X,
                                                      unsigned short* __restrict__ Xb,
                                                      float* __restrict__ sq,
                                                      unsigned* __restrict__ ap2,
                                                      unsigned* __restrict__ an2) {
    int tid = threadIdx.x;
    int row = blockIdx.x * 16 + (tid >> 4);
    int l = tid & 15;
    const float4* p = reinterpret_cast<const float4*>(X + (size_t)row * D + l * 8);
    float4 u = p[0];
    float4 v = p[1];
    float s = u.x*u.x + u.y*u.y + u.z*u.z + u.w*u.w
            + v.x*v.x + v.y*v.y + v.z*v.z + v.w*v.w;
    u16x8 o;
    o[0] = f2bf(u.x); o[1] = f2bf(u.y); o[2] = f2bf(u.z); o[3] = f2bf(u.w);
    o[4] = f2bf(v.x); o[5] = f2bf(v.y); o[6] = f2bf(v.z); o[7] = f2bf(v.w);
    *reinterpret_cast<u16x8*>(Xb + (size_t)row * D + l * 8) = o;
    #pragma unroll
    for (int off = 8; off >= 1; off >>= 1) s += __shfl_xor(s, off);
    if (l == 0) {
        sq[row] = s;
        ap2[row] = 0u;            // 0.0f  (< any clipped d2)
        an2[row] = 0x7F7F7F7Fu;   // huge  (> any d2)
    }
}

// ---------- main: full-Gram, i-mining only ----------
// Strip bi (128 rows) x chunk c (10-11 j-tiles of 64 cols). Every ordered pair
// (i,j) computed exactly once chip-wide -> row-direction mining alone suffices;
// no per-tile cross-lane reduction, no per-tile atomics, no dual bookkeeping.
// A-strip fragments hoisted to registers ONCE (64 VGPRs); the 32 KB A staging
// area is then recycled as a double-buffered B tile -> 1 barrier per tile,
// restage flight hidden under MFMA+epilogue. 32 KB LDS, 3 blocks/CU (VGPR-bound).
// LDS row-major, 16B chunks; LDS chunk slot s of row r holds global chunk s^(r&7).
__global__ __launch_bounds__(256, 3) void triplet_main(
        const unsigned short* __restrict__ Xb,
        const int* __restrict__ lbl,
        const float* __restrict__ sq,
        unsigned* __restrict__ ap2,
        unsigned* __restrict__ an2) {
    __shared__ unsigned short Bs[2][64 * D];   // 32 KB total; also stages A at start
    unsigned short* BsL = &Bs[0][0];

    const int bi = blockIdx.x / CPS;
    const int c  = blockIdx.x - bi * CPS;
    const int jt0 = c * 10 + (c < 8 ? c : 8);       // chunk start tile
    const int cnt = 10 + (c < 8 ? 1 : 0);           // 11 or 10 tiles
    const int i0 = bi * 128;

    const int tid = threadIdx.x;
    const int w = tid >> 6;        // wave 0..3
    const int lane = tid & 63;
    const int wr = w >> 1;         // wave-tile: 64 rows x 32 cols of 128x64 C
    const int wc = w & 1;
    const int quad = lane >> 4;
    const int lx = lane & 15;

    // ---- stage A strip (128 rows) through the B buffers ----
    #pragma unroll
    for (int t = 0; t < 8; ++t) {
        int rbase = w * 32 + t * 4;
        int r = rbase + quad;
        int gc = lx ^ (r & 7);
        gload_lds16(Xb + (size_t)(i0 + r) * D + gc * 8, BsL + rbase * D);
    }

    // row labels for this wave's 16 accumulator rows (hidden under A staging)
    int lbl_i[16];
    #pragma unroll
    for (int tr = 0; tr < 4; ++tr)
        #pragma unroll
        for (int v = 0; v < 4; ++v)
            lbl_i[tr * 4 + v] = lbl[i0 + wr * 64 + tr * 16 + quad * 4 + v];

    __syncthreads();   // A staged

    // ---- hoist A fragments to registers: af_r[tr][ks], 64 VGPRs ----
    bf16x8 af_r[4][4];
    #pragma unroll
    for (int tr = 0; tr < 4; ++tr) {
        int rA = wr * 64 + tr * 16 + lx;
        #pragma unroll
        for (int ks = 0; ks < 4; ++ks) {
            int sc = (ks * 4 + quad) ^ (lx & 7);
            af_r[tr][ks] = *reinterpret_cast<const bf16x8*>(&BsL[rA * D + sc * 8]);
        }
    }
    __syncthreads();   // all waves done reading A region

    // ---- stage B tile 0 into buffer 0 ----
    {
        int jj0 = jt0;
        #pragma unroll
        for (int t = 0; t < 4; ++t) {
            int rbase = w * 16 + t * 4;
            int r = rbase + quad;
            int gc = lx ^ (r & 7);
            gload_lds16(Xb + (size_t)(jj0 * 64 + r) * D + gc * 8, BsL + rbase * D);
        }
    }

    float m_ap[16], m_an[16];
    #pragma unroll
    for (int q = 0; q < 16; ++q) { m_ap[q] = -INFINITY; m_an[q] = INFINITY; }

    __syncthreads();   // B tile 0 drained

    for (int tt = 0; tt < cnt; ++tt) {
        const int jj = jt0 + tt;
        const int cur = tt & 1;
        const unsigned short* curB = BsL + cur * (64 * D);

        // per-lane j metadata first (so the epilogue's wait doesn't drain prefetch)
        float sqj[2]; int lblj[2];
        #pragma unroll
        for (int tc = 0; tc < 2; ++tc) {
            int jc = jj * 64 + wc * 32 + tc * 16 + lx;
            sqj[tc] = sq[jc];
            lblj[tc] = lbl[jc];
        }

        // prefetch next B tile into the other buffer (flight hidden by MFMA+epilogue)
        if (tt + 1 < cnt) {
            unsigned short* nb = BsL + (cur ^ 1) * (64 * D);
            int jn = jj + 1;
            #pragma unroll
            for (int t = 0; t < 4; ++t) {
                int rbase = w * 16 + t * 4;
                int r = rbase + quad;
                int gc = lx ^ (r & 7);
                gload_lds16(Xb + (size_t)(jn * 64 + r) * D + gc * 8, nb + rbase * D);
            }
        }

        f32x4 acc[4][2];
        #pragma unroll
        for (int a = 0; a < 4; ++a)
            #pragma unroll
            for (int cc = 0; cc < 2; ++cc)
                acc[a][cc] = (f32x4){0.f, 0.f, 0.f, 0.f};

        #pragma unroll
        for (int ks = 0; ks < 4; ++ks) {
            bf16x8 bf[2];
            #pragma unroll
            for (int tc = 0; tc < 2; ++tc) {
                int rB = wc * 32 + tc * 16 + lx;
                int sc = (ks * 4 + quad) ^ (lx & 7);
                bf[tc] = *reinterpret_cast<const bf16x8*>(&curB[rB * D + sc * 8]);
            }
            #pragma unroll
            for (int tr = 0; tr < 4; ++tr)
                #pragma unroll
                for (int tc = 0; tc < 2; ++tc)
                    acc[tr][tc] = __builtin_amdgcn_mfma_f32_16x16x32_bf16(
                        af_r[tr][ks], bf[tc], acc[tr][tc], 0, 0, 0);
        }

        // ---- epilogue: i-direction masked mining only ----
        #pragma unroll
        for (int tc = 0; tc < 2; ++tc) {
            #pragma unroll
            for (int tr = 0; tr < 4; ++tr) {
                #pragma unroll
                for (int v = 0; v < 4; ++v) {
                    int q = tr * 4 + v;
                    float vi = fmaf(-2.f, acc[tr][tc][v], sqj[tc]);
                    bool same = (lblj[tc] == lbl_i[q]);
                    m_ap[q] = same ? fmaxf(m_ap[q], vi) : m_ap[q];
                    m_an[q] = same ? m_an[q] : fminf(m_an[q], vi);
                }
            }
        }

        if (tt + 1 < cnt) __syncthreads();   // prefetch drained -> next tile ready
    }

    // reduce over the 16 j-lanes, then one atomic pair per row per wave
    #pragma unroll
    for (int off = 8; off >= 1; off >>= 1) {
        #pragma unroll
        for (int q = 0; q < 16; ++q) {
            m_ap[q] = fmaxf(m_ap[q], __shfl_xor(m_ap[q], off));
            m_an[q] = fminf(m_an[q], __shfl_xor(m_an[q], off));
        }
    }
    if (lx == 0) {
        #pragma unroll
        for (int tr = 0; tr < 4; ++tr) {
            #pragma unroll
            for (int v = 0; v < 4; ++v) {
                int q = tr * 4 + v;
                int row = i0 + wr * 64 + tr * 16 + quad * 4 + v;
                float sqi = sq[row];
                float vap = fmaxf(sqi + m_ap[q], 1e-12f);
                float van = fmaxf(sqi + m_an[q], 1e-12f);
                atomicMax(&ap2[row], __float_as_uint(vap));
                atomicMin(&an2[row], __float_as_uint(van));
            }
        }
    }
}

// ---------- finalize: sqrt + hinge + mean ----------
__global__ __launch_bounds__(1024) void finalize_kernel(const unsigned* __restrict__ ap2,
                                                        const unsigned* __restrict__ an2,
                                                        float* __restrict__ out) {
    int tid = threadIdx.x;
    float ls = 0.f, ps = 0.f;
    for (int row = tid; row < N; row += 1024) {
        float ap = sqrtf(__uint_as_float(ap2[row]));
        float an = sqrtf(__uint_as_float(an2[row]));
        ls += fmaxf(0.f, MARGIN - (an - ap));
        ps += (an > ap) ? 1.f : 0.f;
    }
    #pragma unroll
    for (int off = 32; off >= 1; off >>= 1) {
        ls += __shfl_xor(ls, off);
        ps += __shfl_xor(ps, off);
    }
    __shared__ float red[2][16];
    int w = tid >> 6;
    if ((tid & 63) == 0) { red[0][w] = ls; red[1][w] = ps; }
    __syncthreads();
    if (tid == 0) {
        float L = 0.f, P = 0.f;
        #pragma unroll
        for (int i = 0; i < 16; ++i) { L += red[0][i]; P += red[1][i]; }
        out[0] = L / (float)N;
        out[1] = P / (float)N;
    }
}

extern "C" void kernel_launch(void* const* d_in, const int* in_sizes, int n_in,
                              void* d_out, int out_size, void* d_ws, size_t ws_size,
                              hipStream_t stream) {
    const float* X = (const float*)d_in[0];
    const int* lbl = (const int*)d_in[1];
    float* out = (float*)d_out;

    float* sq = (float*)d_ws;                               // N floats
    unsigned* ap2 = (unsigned*)d_ws + N;                    // N uints
    unsigned* an2 = (unsigned*)d_ws + 2 * N;                // N uints
    unsigned short* Xb = (unsigned short*)((char*)d_ws + 3 * N * sizeof(unsigned)); // N*D bf16

    convert_kernel<<<N / 16, 256, 0, stream>>>(X, Xb, sq, ap2, an2);
    triplet_main<<<GRID_MAIN, 256, 0, stream>>>(Xb, lbl, sq, ap2, an2);
    finalize_kernel<<<1, 1024, 0, stream>>>(ap2, an2, out);
}

// Round 3
// 93.472 us; speedup vs baseline: 1.1215x; 1.1215x over previous
//
#include <hip/hip_runtime.h>
#include <hip/hip_bf16.h>
#include <math.h>

#define N 8192
#define D 128
#define MARGIN 0.3f

#define NSTRIP 64            // 128-row strips
#define CPS 8                // j-chunks per strip
#define TPC 16               // 64-col j-tiles per chunk (8*16 = 128, uniform)
#define GRID_MAIN (NSTRIP * CPS)   // 512 = exactly 2 blocks/CU

typedef float f32x4 __attribute__((ext_vector_type(4)));
typedef short bf16x8 __attribute__((ext_vector_type(8)));
typedef unsigned short u16x8 __attribute__((ext_vector_type(8)));

#define AS1 __attribute__((address_space(1)))
#define AS3 __attribute__((address_space(3)))

__device__ inline void gload_lds16(const void* g, void* l) {
    __builtin_amdgcn_global_load_lds((AS1 void*)(void*)(g), (AS3 void*)(l), 16, 0, 0);
}

__device__ inline unsigned short f2bf(float f) {
    unsigned u = __float_as_uint(f);
    unsigned r = (u + 0x7FFFu + ((u >> 16) & 1u)) >> 16;
    return (unsigned short)r;
}

// ---------- convert fp32 -> bf16 + row norms + init mining arrays ----------
__global__ __launch_bounds__(256) void convert_kernel(const float* __restrict__ X,
                                                      unsigned short* __restrict__ Xb,
                                                      float* __restrict__ sq,
                                                      unsigned* __restrict__ ap2,
                                                      unsigned* __restrict__ an2) {
    int tid = threadIdx.x;
    int row = blockIdx.x * 16 + (tid >> 4);
    int l = tid & 15;
    const float4* p = reinterpret_cast<const float4*>(X + (size_t)row * D + l * 8);
    float4 u = p[0];
    float4 v = p[1];
    float s = u.x*u.x + u.y*u.y + u.z*u.z + u.w*u.w
            + v.x*v.x + v.y*v.y + v.z*v.z + v.w*v.w;
    u16x8 o;
    o[0] = f2bf(u.x); o[1] = f2bf(u.y); o[2] = f2bf(u.z); o[3] = f2bf(u.w);
    o[4] = f2bf(v.x); o[5] = f2bf(v.y); o[6] = f2bf(v.z); o[7] = f2bf(v.w);
    *reinterpret_cast<u16x8*>(Xb + (size_t)row * D + l * 8) = o;
    #pragma unroll
    for (int off = 8; off >= 1; off >>= 1) s += __shfl_xor(s, off);
    if (l == 0) {
        sq[row] = s;
        ap2[row] = 0u;            // 0.0f  (< any clipped d2)
        an2[row] = 0x7F7F7F7Fu;   // huge  (> any d2)
    }
}

// ---------- main: full-Gram, i-mining only, 8-wave blocks, 32x32 wave tiles ----------
// Strip bi (128 rows) x chunk c (16 j-tiles of 64 cols). Grid 512 = exactly
// 2 blocks/CU (16 waves/CU, 50% occupancy — the round-2 kernel's 190-reg waves
// capped at 2 waves/SIMD; 32x32 wave tiles cut state to ~105 regs -> 4/SIMD).
// A-strip fragments hoisted to regs once (32 VGPR/wave); 32 KB LDS = B double
// buffer (also stages A at start). One barrier per tile; B prefetch issued at
// tile top, drained by the end-of-tile barrier. LDS swizzle: chunk slot s of
// row r holds global chunk s^(r&7); ds_read addr = vb ^ (ks<<6) (exact XOR
// decomposition of the swizzle -> 1 VALU op per read).
__global__ __launch_bounds__(512, 4) void triplet_main(
        const unsigned short* __restrict__ Xb,
        const int* __restrict__ lbl,
        const float* __restrict__ sq,
        unsigned* __restrict__ ap2,
        unsigned* __restrict__ an2) {
    __shared__ unsigned short Bs[2][64 * D];   // 32 KB total; stages A at start
    unsigned short* BsL = &Bs[0][0];

    const int bi = blockIdx.x >> 3;            // /CPS
    const int c  = blockIdx.x & 7;
    const int jt0 = c * TPC;
    const int i0 = bi * 128;

    const int tid = threadIdx.x;
    const int w = tid >> 6;        // wave 0..7
    const int lane = tid & 63;
    const int wr = w >> 1;         // 0..3 : 32-row group
    const int wc = w & 1;          // 0..1 : 32-col group
    const int quad = lane >> 4;
    const int lx = lane & 15;

    // ---- stage A strip (128 rows x 16 chunks) through the B buffers ----
    #pragma unroll
    for (int t = 0; t < 4; ++t) {
        int rbase = w * 16 + t * 4;
        int r = rbase + quad;
        int gc = lx ^ (r & 7);
        gload_lds16(Xb + (size_t)(i0 + r) * D + gc * 8, BsL + rbase * D);
    }

    // row labels for this wave's 8 accumulator rows (hidden under A staging)
    int lbl_i[8];
    #pragma unroll
    for (int tr = 0; tr < 2; ++tr)
        #pragma unroll
        for (int v = 0; v < 4; ++v)
            lbl_i[tr * 4 + v] = lbl[i0 + wr * 32 + tr * 16 + quad * 4 + v];

    __syncthreads();   // A staged

    // ---- hoist A fragments to registers: af_r[tr][ks], 32 VGPRs ----
    bf16x8 af_r[2][4];
    #pragma unroll
    for (int tr = 0; tr < 2; ++tr) {
        int rA = wr * 32 + tr * 16 + lx;
        #pragma unroll
        for (int ks = 0; ks < 4; ++ks) {
            int sc = (ks * 4 + quad) ^ (lx & 7);
            af_r[tr][ks] = *reinterpret_cast<const bf16x8*>(&BsL[rA * D + sc * 8]);
        }
    }
    __syncthreads();   // all waves done reading A region

    // ---- stage B tile 0 into buffer 0 ----
    #pragma unroll
    for (int t = 0; t < 2; ++t) {
        int rbase = w * 8 + t * 4;
        int r = rbase + quad;
        int gc = lx ^ (r & 7);
        gload_lds16(Xb + (size_t)(jt0 * 64 + r) * D + gc * 8, BsL + rbase * D);
    }

    // precomputed swizzled LDS byte offsets for B-frag reads:
    // byte = rB*256 + sc*16, sc = (ks*4+quad)^(lx&7)
    //      = [rB*256 + ((lx&4)<<4) + ((quad^(lx&3))<<4)] ^ (ks<<6)
    unsigned vb[2];
    #pragma unroll
    for (int tc = 0; tc < 2; ++tc) {
        int rB = wc * 32 + tc * 16 + lx;
        vb[tc] = (unsigned)(rB * 256 + ((lx & 4) << 4) + ((quad ^ (lx & 3)) << 4));
    }

    float m_ap[8], m_an[8];
    #pragma unroll
    for (int q = 0; q < 8; ++q) { m_ap[q] = -INFINITY; m_an[q] = INFINITY; }
    const f32x4 z4 = {0.f, 0.f, 0.f, 0.f};

    __syncthreads();   // B tile 0 drained

    #pragma unroll 2
    for (int tt = 0; tt < TPC; ++tt) {
        const int jj = jt0 + tt;
        const int cur = tt & 1;
        const char* bsb = (const char*)BsL + cur * (64 * D * 2);

        // per-lane j metadata (L2-hot; consumed in the epilogue)
        float sqj[2]; int lblj[2];
        #pragma unroll
        for (int tc = 0; tc < 2; ++tc) {
            int jc = jj * 64 + wc * 32 + tc * 16 + lx;
            sqj[tc] = sq[jc];
            lblj[tc] = lbl[jc];
        }

        // prefetch next B tile into the other buffer (drained by end barrier)
        if (tt + 1 < TPC) {
            unsigned short* nb = BsL + (cur ^ 1) * (64 * D);
            int jn = jj + 1;
            #pragma unroll
            for (int t = 0; t < 2; ++t) {
                int rbase = w * 8 + t * 4;
                int r = rbase + quad;
                int gc = lx ^ (r & 7);
                gload_lds16(Xb + (size_t)(jn * 64 + r) * D + gc * 8, nb + rbase * D);
            }
        }

        // ---- MFMA: ks=0 peeled with zero-C (no per-tile acc zeroing) ----
        f32x4 acc[2][2];
        {
            bf16x8 bf0[2];
            #pragma unroll
            for (int tc = 0; tc < 2; ++tc)
                bf0[tc] = *reinterpret_cast<const bf16x8*>(bsb + (vb[tc] ^ 0u));
            #pragma unroll
            for (int tr = 0; tr < 2; ++tr)
                #pragma unroll
                for (int tc = 0; tc < 2; ++tc)
                    acc[tr][tc] = __builtin_amdgcn_mfma_f32_16x16x32_bf16(
                        af_r[tr][0], bf0[tc], z4, 0, 0, 0);
        }
        #pragma unroll
        for (int ks = 1; ks < 4; ++ks) {
            bf16x8 bf[2];
            #pragma unroll
            for (int tc = 0; tc < 2; ++tc)
                bf[tc] = *reinterpret_cast<const bf16x8*>(bsb + (vb[tc] ^ (unsigned)(ks << 6)));
            #pragma unroll
            for (int tr = 0; tr < 2; ++tr)
                #pragma unroll
                for (int tc = 0; tc < 2; ++tc)
                    acc[tr][tc] = __builtin_amdgcn_mfma_f32_16x16x32_bf16(
                        af_r[tr][ks], bf[tc], acc[tr][tc], 0, 0, 0);
        }

        // ---- epilogue: i-direction masked mining (16 candidates/lane) ----
        #pragma unroll
        for (int tc = 0; tc < 2; ++tc) {
            #pragma unroll
            for (int tr = 0; tr < 2; ++tr) {
                #pragma unroll
                for (int v = 0; v < 4; ++v) {
                    int q = tr * 4 + v;
                    float vi = fmaf(-2.f, acc[tr][tc][v], sqj[tc]);
                    bool same = (lblj[tc] == lbl_i[q]);
                    m_ap[q] = same ? fmaxf(m_ap[q], vi) : m_ap[q];
                    m_an[q] = same ? m_an[q] : fminf(m_an[q], vi);
                }
            }
        }

        if (tt + 1 < TPC) __syncthreads();   // prefetch drained -> next tile ready
    }

    // reduce over the 16 j-lanes, then one atomic pair per row (lx==0 lanes)
    #pragma unroll
    for (int off = 8; off >= 1; off >>= 1) {
        #pragma unroll
        for (int q = 0; q < 8; ++q) {
            m_ap[q] = fmaxf(m_ap[q], __shfl_xor(m_ap[q], off));
            m_an[q] = fminf(m_an[q], __shfl_xor(m_an[q], off));
        }
    }
    if (lx == 0) {
        #pragma unroll
        for (int tr = 0; tr < 2; ++tr) {
            #pragma unroll
            for (int v = 0; v < 4; ++v) {
                int q = tr * 4 + v;
                int row = i0 + wr * 32 + tr * 16 + quad * 4 + v;
                float sqi = sq[row];
                float vap = fmaxf(sqi + m_ap[q], 1e-12f);
                float van = fmaxf(sqi + m_an[q], 1e-12f);
                atomicMax(&ap2[row], __float_as_uint(vap));
                atomicMin(&an2[row], __float_as_uint(van));
            }
        }
    }
}

// ---------- finalize: sqrt + hinge + mean ----------
__global__ __launch_bounds__(1024) void finalize_kernel(const unsigned* __restrict__ ap2,
                                                        const unsigned* __restrict__ an2,
                                                        float* __restrict__ out) {
    int tid = threadIdx.x;
    float ls = 0.f, ps = 0.f;
    for (int row = tid; row < N; row += 1024) {
        float ap = sqrtf(__uint_as_float(ap2[row]));
        float an = sqrtf(__uint_as_float(an2[row]));
        ls += fmaxf(0.f, MARGIN - (an - ap));
        ps += (an > ap) ? 1.f : 0.f;
    }
    #pragma unroll
    for (int off = 32; off >= 1; off >>= 1) {
        ls += __shfl_xor(ls, off);
        ps += __shfl_xor(ps, off);
    }
    __shared__ float red[2][16];
    int w = tid >> 6;
    if ((tid & 63) == 0) { red[0][w] = ls; red[1][w] = ps; }
    __syncthreads();
    if (tid == 0) {
        float L = 0.f, P = 0.f;
        #pragma unroll
        for (int i = 0; i < 16; ++i) { L += red[0][i]; P += red[1][i]; }
        out[0] = L / (float)N;
        out[1] = P / (float)N;
    }
}

extern "C" void kernel_launch(void* const* d_in, const int* in_sizes, int n_in,
                              void* d_out, int out_size, void* d_ws, size_t ws_size,
                              hipStream_t stream) {
    const float* X = (const float*)d_in[0];
    const int* lbl = (const int*)d_in[1];
    float* out = (float*)d_out;

    float* sq = (float*)d_ws;                               // N floats
    unsigned* ap2 = (unsigned*)d_ws + N;                    // N uints
    unsigned* an2 = (unsigned*)d_ws + 2 * N;                // N uints
    unsigned short* Xb = (unsigned short*)((char*)d_ws + 3 * N * sizeof(unsigned)); // N*D bf16

    convert_kernel<<<N / 16, 256, 0, stream>>>(X, Xb, sq, ap2, an2);
    triplet_main<<<GRID_MAIN, 512, 0, stream>>>(Xb, lbl, sq, ap2, an2);
    finalize_kernel<<<1, 1024, 0, stream>>>(ap2, an2, out);
}